// Round 3
// baseline (221.360 us; speedup 1.0000x reference)
//
#include <hip/hip_runtime.h>
#include <hip/hip_bf16.h>
#include <math.h>

typedef __attribute__((ext_vector_type(8))) __bf16 bf16x8;
typedef __attribute__((ext_vector_type(4))) float f32x4;

#define NTOK 8192
#define DIN 1024
#define DOUT 1024
#define KAUG 4096
#define SEH 32

#define BM 256
#define BN 128
#define BK 64
#define NKT (KAUG / BK)

static __device__ __forceinline__ unsigned short f2bf(float f) {
  union { float f; unsigned u; } v; v.f = f;
  unsigned r = (v.u + 0x7FFFu + ((v.u >> 16) & 1u)) >> 16;
  return (unsigned short)r;
}
static __device__ __forceinline__ float bflo(unsigned u) {
  union { unsigned u; float f; } v; v.u = u << 16; return v.f;
}
static __device__ __forceinline__ float bfhi(unsigned u) {
  union { unsigned u; float f; } v; v.u = u & 0xFFFF0000u; return v.f;
}

// A_aug[n][i*4 + {0..3}] = { x, b0/s, b1/s, b2/s }  (bf16)
__global__ __launch_bounds__(256) void build_aaug(const float* __restrict__ x,
                                                  ushort* __restrict__ Aaug) {
  const int id = blockIdx.x * 256 + threadIdx.x;
  const float v = x[id];
  const float d0 = fabsf(v + 1.f), d1 = fabsf(v), d2 = fabsf(v - 1.f);
  float b0 = (d0 < 1.f) ? (1.f - d0) * (1.f - d0) : 0.f;
  float b1 = (d1 < 1.f) ? (1.f - d1) * (1.f - d1) : 0.f;
  float b2 = (d2 < 1.f) ? (1.f - d2) * (1.f - d2) : 0.f;
  const float inv = 1.f / (b0 + b1 + b2 + 1e-6f);
  ushort4 o;
  o.x = f2bf(v);
  o.y = f2bf(b0 * inv);
  o.z = f2bf(b1 * inv);
  o.w = f2bf(b2 * inv);
  ((ushort4*)Aaug)[id] = o;
}

// W_aug[o][i*4 + {0..3}] = { base_w[o,i], spline_w[o,i,0..2] }  (bf16)
__global__ __launch_bounds__(256) void pack_w(const float* __restrict__ bw,
                                              const float* __restrict__ sw,
                                              ushort* __restrict__ Waug) {
  const int id = blockIdx.x * 256 + threadIdx.x;
  ushort4 o;
  o.x = f2bf(bw[id]);
  o.y = f2bf(sw[id * 3 + 0]);
  o.z = f2bf(sw[id * 3 + 1]);
  o.w = f2bf(sw[id * 3 + 2]);
  ((ushort4*)Waug)[id] = o;
}

__global__ __launch_bounds__(256) void pack_se(const float* __restrict__ w1,
                                               const float* __restrict__ w2,
                                               ushort* __restrict__ w1b,
                                               ushort* __restrict__ w2b) {
  const int id = blockIdx.x * 256 + threadIdx.x;
  if (id < SEH * DOUT) w1b[id] = f2bf(w1[id]);
  else w2b[id - SEH * DOUT] = f2bf(w2[id - SEH * DOUT]);
}

#define WAITVM(N) asm volatile("s_waitcnt vmcnt(" #N ")" ::: "memory")

// C[8192][1024] = A[8192][4096] * B[1024][4096]^T  (bf16 in, f32 out)
// BM=256 BN=128 BK=64, 8 waves (4Mx2N, per-wave 64x64), tri-buffered LDS,
// T2 XOR-swizzle, T4 counted vmcnt, T5 setprio, T1 XCD chunked swizzle.
__global__ __launch_bounds__(512, 2) void gemm8p(const ushort* __restrict__ A,
                                                 const ushort* __restrict__ B,
                                                 float* __restrict__ C) {
  __shared__ ushort As[3][BM * BK];  // 3 x 32 KB
  __shared__ ushort Bs[3][BN * BK];  // 3 x 16 KB
  const int tid = threadIdx.x;
  const int wid = tid >> 6, lane = tid & 63;
  const int l16 = lane & 15, lk = lane >> 4;
  const int wr = wid >> 1, wc = wid & 1;  // 4x2 wave grid

  // T1: XCD chunked swizzle (grid 256, 8 XCDs -> 32 consecutive per XCD)
  const int swz = (blockIdx.x & 7) * 32 + (blockIdx.x >> 3);
  const int bm = swz >> 3, bn = swz & 7;  // bn inner: XCD shares bm-chunk

  const ushort* Ab = A + (size_t)bm * BM * KAUG;
  const ushort* Bb = B + (size_t)bn * BN * KAUG;

  // staging: lane L covers row (8g + L>>3), source col-block (L&7)^(L>>3)
  const int lrow = lane >> 3;
  const int lcb = (lane & 7) ^ lrow;

  f32x4 acc[4][4] = {};

#define STAGE_A(kt, buf, r)                                                    \
  __builtin_amdgcn_global_load_lds(                                            \
      (const __attribute__((address_space(1))) void*)(Ab +                     \
          (size_t)((r * 8 + wid) * 8 + lrow) * KAUG + (kt) * BK + lcb * 8),    \
      (__attribute__((address_space(3))) void*)(&As[buf][(r * 8 + wid) * 512]),\
      16, 0, 0)
#define STAGE_B(kt, buf, r)                                                    \
  __builtin_amdgcn_global_load_lds(                                            \
      (const __attribute__((address_space(1))) void*)(Bb +                     \
          (size_t)((r * 8 + wid) * 8 + lrow) * KAUG + (kt) * BK + lcb * 8),    \
      (__attribute__((address_space(3))) void*)(&Bs[buf][(r * 8 + wid) * 512]),\
      16, 0, 0)

  // prologue: stage tiles 0 and 1 (6 loads each per wave -> 12 outstanding)
  STAGE_A(0, 0, 0); STAGE_A(0, 0, 1); STAGE_A(0, 0, 2); STAGE_A(0, 0, 3);
  STAGE_B(0, 0, 0); STAGE_B(0, 0, 1);
  STAGE_A(1, 1, 0); STAGE_A(1, 1, 1); STAGE_A(1, 1, 2); STAGE_A(1, 1, 3);
  STAGE_B(1, 1, 0); STAGE_B(1, 1, 1);

  int bc = 0, bs = 2;  // compute buf (kt%3), stage buf ((kt+2)%3)
  for (int kt = 0; kt < NKT; ++kt) {
    // tile-start wait: S(kt) done; S(kt+1) (6 loads) stays in flight
    if (kt <= NKT - 2) WAITVM(6); else WAITVM(0);
    __builtin_amdgcn_s_barrier();

    const bool pf = (kt < NKT - 2);
#pragma unroll
    for (int q = 0; q < 4; ++q) {
      const int mi = (q >> 1) * 2, ni = (q & 1) * 2;
      // prefetch S(kt+2): 3 issues in ph0, 3 in ph1
      if (q == 0 && pf) { STAGE_A(kt + 2, bs, 0); STAGE_A(kt + 2, bs, 1); STAGE_B(kt + 2, bs, 0); }
      if (q == 1 && pf) { STAGE_A(kt + 2, bs, 2); STAGE_A(kt + 2, bs, 3); STAGE_B(kt + 2, bs, 1); }
      bf16x8 af[2][2], bfr[2][2];
#pragma unroll
      for (int m2 = 0; m2 < 2; ++m2)
#pragma unroll
        for (int k2 = 0; k2 < 2; ++k2) {
          const int row = wr * 64 + (mi + m2) * 16 + l16;
          const int cb = k2 * 4 + lk;
          af[m2][k2] = *(const bf16x8*)&As[bc][row * 64 + ((cb ^ (l16 & 7)) << 3)];
        }
#pragma unroll
      for (int n2 = 0; n2 < 2; ++n2)
#pragma unroll
        for (int k2 = 0; k2 < 2; ++k2) {
          const int row = wc * 64 + (ni + n2) * 16 + l16;
          const int cb = k2 * 4 + lk;
          bfr[n2][k2] = *(const bf16x8*)&Bs[bc][row * 64 + ((cb ^ (l16 & 7)) << 3)];
        }
      __builtin_amdgcn_s_barrier();
      __builtin_amdgcn_s_setprio(1);
#pragma unroll
      for (int m2 = 0; m2 < 2; ++m2)
#pragma unroll
        for (int n2 = 0; n2 < 2; ++n2)
#pragma unroll
          for (int k2 = 0; k2 < 2; ++k2)
            acc[mi + m2][ni + n2] = __builtin_amdgcn_mfma_f32_16x16x32_bf16(
                af[m2][k2], bfr[n2][k2], acc[mi + m2][ni + n2], 0, 0, 0);
      __builtin_amdgcn_s_setprio(0);
    }
    __builtin_amdgcn_s_barrier();  // all reads of As[bc] retired before overwrite
    bc = (bc == 2) ? 0 : bc + 1;
    bs = (bs == 2) ? 0 : bs + 1;
  }

  // C/D layout: col = lane&15, row = (lane>>4)*4 + reg
  float* Cb = C + (size_t)(bm * BM + wr * 64) * DOUT + bn * BN + wc * 64;
#pragma unroll
  for (int m = 0; m < 4; ++m)
#pragma unroll
    for (int n = 0; n < 4; ++n)
#pragma unroll
      for (int j = 0; j < 4; ++j)
        Cb[(size_t)(m * 16 + lk * 4 + j) * DOUT + n * 16 + l16] = acc[m][n][j];
}

// Fused LayerNorm + SE gate, one WAVE per token, all-register.
__global__ __launch_bounds__(256) void ln_se_fused(
    float* __restrict__ out,
    const float* __restrict__ ln_w, const float* __restrict__ ln_b,
    const ushort* __restrict__ w1b, const float* __restrict__ se_b1,
    const ushort* __restrict__ w2b, const float* __restrict__ se_b2) {
  const int lane = threadIdx.x & 63;
  const int t = blockIdx.x * 4 + (threadIdx.x >> 6);
  float* row = out + (size_t)t * DOUT;

  float y[16];
#pragma unroll
  for (int h = 0; h < 2; ++h) {
    const float4 a = ((const float4*)row)[(lane + 64 * h) * 2];
    const float4 b = ((const float4*)row)[(lane + 64 * h) * 2 + 1];
    y[h * 8 + 0] = a.x; y[h * 8 + 1] = a.y; y[h * 8 + 2] = a.z; y[h * 8 + 3] = a.w;
    y[h * 8 + 4] = b.x; y[h * 8 + 5] = b.y; y[h * 8 + 6] = b.z; y[h * 8 + 7] = b.w;
  }
  float s = 0.f, ss = 0.f;
#pragma unroll
  for (int e = 0; e < 16; ++e) { s += y[e]; ss += y[e] * y[e]; }
#pragma unroll
  for (int m = 32; m; m >>= 1) { s += __shfl_xor(s, m); ss += __shfl_xor(ss, m); }
  const float mu = s * (1.f / (float)DOUT);
  const float inv = rsqrtf(ss * (1.f / (float)DOUT) - mu * mu + 1e-5f);

#pragma unroll
  for (int h = 0; h < 2; ++h) {
    const float4 lw0 = ((const float4*)ln_w)[(lane + 64 * h) * 2];
    const float4 lw1 = ((const float4*)ln_w)[(lane + 64 * h) * 2 + 1];
    const float4 lb0 = ((const float4*)ln_b)[(lane + 64 * h) * 2];
    const float4 lb1 = ((const float4*)ln_b)[(lane + 64 * h) * 2 + 1];
    y[h * 8 + 0] = (y[h * 8 + 0] - mu) * inv * lw0.x + lb0.x;
    y[h * 8 + 1] = (y[h * 8 + 1] - mu) * inv * lw0.y + lb0.y;
    y[h * 8 + 2] = (y[h * 8 + 2] - mu) * inv * lw0.z + lb0.z;
    y[h * 8 + 3] = (y[h * 8 + 3] - mu) * inv * lw0.w + lb0.w;
    y[h * 8 + 4] = (y[h * 8 + 4] - mu) * inv * lw1.x + lb1.x;
    y[h * 8 + 5] = (y[h * 8 + 5] - mu) * inv * lw1.y + lb1.y;
    y[h * 8 + 6] = (y[h * 8 + 6] - mu) * inv * lw1.z + lb1.z;
    y[h * 8 + 7] = (y[h * 8 + 7] - mu) * inv * lw1.w + lb1.w;
  }

  float hj[32];
#pragma unroll
  for (int j = 0; j < 32; ++j) {
    float p = 0.f;
#pragma unroll
    for (int h = 0; h < 2; ++h) {
      const uint4 w = *(const uint4*)(w1b + j * DOUT + (lane + 64 * h) * 8);
      p += y[h * 8 + 0] * bflo(w.x) + y[h * 8 + 1] * bfhi(w.x)
         + y[h * 8 + 2] * bflo(w.y) + y[h * 8 + 3] * bfhi(w.y)
         + y[h * 8 + 4] * bflo(w.z) + y[h * 8 + 5] * bfhi(w.z)
         + y[h * 8 + 6] * bflo(w.w) + y[h * 8 + 7] * bfhi(w.w);
    }
    hj[j] = p;
  }
#pragma unroll
  for (int m = 32; m; m >>= 1)
#pragma unroll
    for (int j = 0; j < 32; ++j) hj[j] += __shfl_xor(hj[j], m);
#pragma unroll
  for (int j = 0; j < 32; ++j) hj[j] = fmaxf(hj[j] + se_b1[j], 0.f);

#pragma unroll
  for (int h = 0; h < 2; ++h) {
    float o[8];
#pragma unroll
    for (int e = 0; e < 8; ++e) {
      const int c = (lane + 64 * h) * 8 + e;
      const uint4* wp = (const uint4*)(w2b + (size_t)c * SEH);
      const uint4 wa = wp[0], wb = wp[1], wc2 = wp[2], wd = wp[3];
      float g = se_b2[c];
      g += hj[0] * bflo(wa.x) + hj[1] * bfhi(wa.x) + hj[2] * bflo(wa.y) + hj[3] * bfhi(wa.y)
         + hj[4] * bflo(wa.z) + hj[5] * bfhi(wa.z) + hj[6] * bflo(wa.w) + hj[7] * bfhi(wa.w);
      g += hj[8] * bflo(wb.x) + hj[9] * bfhi(wb.x) + hj[10] * bflo(wb.y) + hj[11] * bfhi(wb.y)
         + hj[12] * bflo(wb.z) + hj[13] * bfhi(wb.z) + hj[14] * bflo(wb.w) + hj[15] * bfhi(wb.w);
      g += hj[16] * bflo(wc2.x) + hj[17] * bfhi(wc2.x) + hj[18] * bflo(wc2.y) + hj[19] * bfhi(wc2.y)
         + hj[20] * bflo(wc2.z) + hj[21] * bfhi(wc2.z) + hj[22] * bflo(wc2.w) + hj[23] * bfhi(wc2.w);
      g += hj[24] * bflo(wd.x) + hj[25] * bfhi(wd.x) + hj[26] * bflo(wd.y) + hj[27] * bfhi(wd.y)
         + hj[28] * bflo(wd.z) + hj[29] * bfhi(wd.z) + hj[30] * bflo(wd.w) + hj[31] * bfhi(wd.w);
      o[e] = y[h * 8 + e] / (1.f + __expf(-g));
    }
    float4 s0, s1;
    s0.x = o[0]; s0.y = o[1]; s0.z = o[2]; s0.w = o[3];
    s1.x = o[4]; s1.y = o[5]; s1.z = o[6]; s1.w = o[7];
    ((float4*)row)[(lane + 64 * h) * 2] = s0;
    ((float4*)row)[(lane + 64 * h) * 2 + 1] = s1;
  }
}

extern "C" void kernel_launch(void* const* d_in, const int* in_sizes, int n_in,
                              void* d_out, int out_size, void* d_ws, size_t ws_size,
                              hipStream_t stream) {
  const float* x = (const float*)d_in[0];
  const float* bw = (const float*)d_in[1];
  const float* sw = (const float*)d_in[2];
  const float* ln_w = (const float*)d_in[3];
  const float* ln_b = (const float*)d_in[4];
  const float* se_w1 = (const float*)d_in[5];
  const float* se_b1 = (const float*)d_in[6];
  const float* se_w2 = (const float*)d_in[7];
  const float* se_b2 = (const float*)d_in[8];
  float* out = (float*)d_out;

  ushort* Aaug = (ushort*)d_ws;                        // 64 MB
  ushort* Waug = Aaug + (size_t)NTOK * KAUG;           // 8 MB
  ushort* w1b = Waug + (size_t)DOUT * KAUG;            // 64 KB
  ushort* w2b = w1b + SEH * DOUT;                      // 64 KB

  build_aaug<<<NTOK * DIN / 256, 256, 0, stream>>>(x, Aaug);
  pack_w<<<DOUT * DIN / 256, 256, 0, stream>>>(bw, sw, Waug);
  pack_se<<<2 * SEH * DOUT / 256, 256, 0, stream>>>(se_w1, se_w2, w1b, w2b);
  gemm8p<<<(NTOK / BM) * (DOUT / BN), 512, 0, stream>>>(Aaug, Waug, out);
  ln_se_fused<<<NTOK / 4, 256, 0, stream>>>(out, ln_w, ln_b, w1b, se_b1, w2b, se_b2);
}

// Round 4
// 183.833 us; speedup vs baseline: 1.2041x; 1.2041x over previous
//
#include <hip/hip_runtime.h>
#include <hip/hip_bf16.h>
#include <math.h>

typedef __attribute__((ext_vector_type(8))) __bf16 bf16x8;
typedef __attribute__((ext_vector_type(4))) float f32x4;

#define NTOK 8192
#define DIN 1024
#define DOUT 1024
#define KAUG 4096
#define SEH 32

#define BK 64
#define KHALF 2048
#define NKT (KHALF / BK)  // 32

static __device__ __forceinline__ unsigned short f2bf(float f) {
  union { float f; unsigned u; } v; v.f = f;
  unsigned r = (v.u + 0x7FFFu + ((v.u >> 16) & 1u)) >> 16;
  return (unsigned short)r;
}
static __device__ __forceinline__ float bflo(unsigned u) {
  union { unsigned u; float f; } v; v.u = u << 16; return v.f;
}
static __device__ __forceinline__ float bfhi(unsigned u) {
  union { unsigned u; float f; } v; v.u = u & 0xFFFF0000u; return v.f;
}

// A_aug[n][i*4 + {0..3}] = { x, b0/s, b1/s, b2/s }  (bf16)
__global__ __launch_bounds__(256) void build_aaug(const float* __restrict__ x,
                                                  ushort* __restrict__ Aaug) {
  const int id = blockIdx.x * 256 + threadIdx.x;
  const float v = x[id];
  const float d0 = fabsf(v + 1.f), d1 = fabsf(v), d2 = fabsf(v - 1.f);
  float b0 = (d0 < 1.f) ? (1.f - d0) * (1.f - d0) : 0.f;
  float b1 = (d1 < 1.f) ? (1.f - d1) * (1.f - d1) : 0.f;
  float b2 = (d2 < 1.f) ? (1.f - d2) * (1.f - d2) : 0.f;
  const float inv = 1.f / (b0 + b1 + b2 + 1e-6f);
  ushort4 o;
  o.x = f2bf(v);
  o.y = f2bf(b0 * inv);
  o.z = f2bf(b1 * inv);
  o.w = f2bf(b2 * inv);
  ((ushort4*)Aaug)[id] = o;
}

// W_aug[o][i*4 + {0..3}] = { base_w[o,i], spline_w[o,i,0..2] }  (bf16)
__global__ __launch_bounds__(256) void pack_w(const float* __restrict__ bw,
                                              const float* __restrict__ sw,
                                              ushort* __restrict__ Waug) {
  const int id = blockIdx.x * 256 + threadIdx.x;
  ushort4 o;
  o.x = f2bf(bw[id]);
  o.y = f2bf(sw[id * 3 + 0]);
  o.z = f2bf(sw[id * 3 + 1]);
  o.w = f2bf(sw[id * 3 + 2]);
  ((ushort4*)Waug)[id] = o;
}

__global__ __launch_bounds__(256) void pack_se(const float* __restrict__ w1,
                                               const float* __restrict__ w2,
                                               ushort* __restrict__ w1b,
                                               ushort* __restrict__ w2b) {
  const int id = blockIdx.x * 256 + threadIdx.x;
  if (id < SEH * DOUT) w1b[id] = f2bf(w1[id]);
  else w2b[id - SEH * DOUT] = f2bf(w2[id - SEH * DOUT]);
}

#define WAITVM(N) asm volatile("s_waitcnt vmcnt(" #N ")" ::: "memory")

// Split-K GEMM: C-tile 256x256, K split in 2 halves of 2048.
// 8 waves (2M x 4N), per-wave 128x64 (acc[8][4]). Double-buffered 128KB LDS.
// kh=0 -> P0 (d_out), kh=1 -> P1 (ws). ln_se sums the partials.
__global__ __launch_bounds__(512, 2) void gemm_sk(const ushort* __restrict__ A,
                                                  const ushort* __restrict__ B,
                                                  float* __restrict__ P0,
                                                  float* __restrict__ P1) {
  __shared__ ushort As[2][256 * BK];  // 2 x 32 KB
  __shared__ ushort Bs[2][256 * BK];  // 2 x 32 KB
  const int tid = threadIdx.x;
  const int wid = tid >> 6, lane = tid & 63;
  const int l16 = lane & 15, lk = lane >> 4;
  const int wm = wid >> 2, wn = wid & 3;  // 2M x 4N wave grid

  // T1: XCD chunked swizzle. g = xcd*32 + slot; chunk shares kh + bm rows.
  const int g = (blockIdx.x & 7) * 32 + (blockIdx.x >> 3);
  const int kh = g >> 7;          // 0..1
  const int bm = (g & 127) >> 2;  // 0..31
  const int bn = g & 3;           // 0..3

  const ushort* Ab = A + (size_t)bm * 256 * KAUG + kh * KHALF;
  const ushort* Bb = B + (size_t)bn * 256 * KAUG + kh * KHALF;
  float* P = kh ? P1 : P0;

  const int lrow = lane >> 3;            // 0..7
  const int lcb = (lane & 7) ^ lrow;     // inverse-swizzled source col-block

  f32x4 acc[8][4] = {};

  // stage: per thread 4 A chunks + 4 B chunks of 16B per K-tile.
  // LDS chunk c = r*512 + wid*64 + lane -> row = r*64+wid*8+lrow, dest col = lane&7,
  // source col-block = lcb (involution swizzle, conflict-free ds_read later).
#define STAGE_A(kt, buf, r)                                                     \
  __builtin_amdgcn_global_load_lds(                                             \
      (const __attribute__((address_space(1))) void*)(Ab +                      \
          (size_t)((r) * 64 + wid * 8 + lrow) * KAUG + (kt) * BK + lcb * 8),    \
      (__attribute__((address_space(3))) void*)(&As[buf][((r) * 512 + wid * 64) * 8]), \
      16, 0, 0)
#define STAGE_B(kt, buf, r)                                                     \
  __builtin_amdgcn_global_load_lds(                                             \
      (const __attribute__((address_space(1))) void*)(Bb +                      \
          (size_t)((r) * 64 + wid * 8 + lrow) * KAUG + (kt) * BK + lcb * 8),    \
      (__attribute__((address_space(3))) void*)(&Bs[buf][((r) * 512 + wid * 64) * 8]), \
      16, 0, 0)
#define STAGE_ALL(kt, buf)                                                      \
  do {                                                                          \
    STAGE_A(kt, buf, 0); STAGE_A(kt, buf, 1); STAGE_A(kt, buf, 2); STAGE_A(kt, buf, 3); \
    STAGE_B(kt, buf, 0); STAGE_B(kt, buf, 1); STAGE_B(kt, buf, 2); STAGE_B(kt, buf, 3); \
  } while (0)

  // fragment read (element units): row*64 + ((cb ^ (l16&7))*8), cb = kk*4+lk
#define RD_A(buf, m, kk) \
  (*(const bf16x8*)&As[buf][(wm * 128 + (m) * 16 + l16) * 64 + ((((kk) * 4 + lk) ^ (l16 & 7)) << 3)])
#define RD_B(buf, n, kk) \
  (*(const bf16x8*)&Bs[buf][(wn * 64 + (n) * 16 + l16) * 64 + ((((kk) * 4 + lk) ^ (l16 & 7)) << 3)])

  // prologue: stage tile 0 into buf 0
  STAGE_ALL(0, 0);

  int bc = 0;
  for (int kt = 0; kt < NKT; ++kt) {
    // issue next tile's 8 loads BEFORE the counted wait (never drain mid-loop)
    if (kt < NKT - 1) {
      STAGE_ALL(kt + 1, bc ^ 1);
      WAITVM(8);
    } else {
      WAITVM(0);
    }
    __builtin_amdgcn_s_barrier();

    bf16x8 a0[4][2], a1[4][2], b0[2][2], b1[2][2];
    // ph0: read A0 + B0, MFMA m0-3 x n0-1
#pragma unroll
    for (int m = 0; m < 4; ++m) { a0[m][0] = RD_A(bc, m, 0); a0[m][1] = RD_A(bc, m, 1); }
#pragma unroll
    for (int n = 0; n < 2; ++n) { b0[n][0] = RD_B(bc, n, 0); b0[n][1] = RD_B(bc, n, 1); }
    __builtin_amdgcn_s_setprio(1);
#pragma unroll
    for (int m = 0; m < 4; ++m)
#pragma unroll
      for (int n = 0; n < 2; ++n)
#pragma unroll
        for (int k2 = 0; k2 < 2; ++k2)
          acc[m][n] = __builtin_amdgcn_mfma_f32_16x16x32_bf16(a0[m][k2], b0[n][k2], acc[m][n], 0, 0, 0);
    __builtin_amdgcn_s_setprio(0);
    __builtin_amdgcn_s_barrier();

    // ph1: read B1, MFMA m0-3 x n2-3 (A0 dies after)
#pragma unroll
    for (int n = 0; n < 2; ++n) { b1[n][0] = RD_B(bc, n + 2, 0); b1[n][1] = RD_B(bc, n + 2, 1); }
    __builtin_amdgcn_s_setprio(1);
#pragma unroll
    for (int m = 0; m < 4; ++m)
#pragma unroll
      for (int n = 0; n < 2; ++n)
#pragma unroll
        for (int k2 = 0; k2 < 2; ++k2)
          acc[m][n + 2] = __builtin_amdgcn_mfma_f32_16x16x32_bf16(a0[m][k2], b1[n][k2], acc[m][n + 2], 0, 0, 0);
    __builtin_amdgcn_s_setprio(0);
    __builtin_amdgcn_s_barrier();

    // ph2: read A1, MFMA m4-7 x n0-1 (B0 dies after)
#pragma unroll
    for (int m = 0; m < 4; ++m) { a1[m][0] = RD_A(bc, m + 4, 0); a1[m][1] = RD_A(bc, m + 4, 1); }
    __builtin_amdgcn_s_setprio(1);
#pragma unroll
    for (int m = 0; m < 4; ++m)
#pragma unroll
      for (int n = 0; n < 2; ++n)
#pragma unroll
        for (int k2 = 0; k2 < 2; ++k2)
          acc[m + 4][n] = __builtin_amdgcn_mfma_f32_16x16x32_bf16(a1[m][k2], b0[n][k2], acc[m + 4][n], 0, 0, 0);
    __builtin_amdgcn_s_setprio(0);
    __builtin_amdgcn_s_barrier();

    // ph3: MFMA m4-7 x n2-3
    __builtin_amdgcn_s_setprio(1);
#pragma unroll
    for (int m = 0; m < 4; ++m)
#pragma unroll
      for (int n = 0; n < 2; ++n)
#pragma unroll
        for (int k2 = 0; k2 < 2; ++k2)
          acc[m + 4][n + 2] = __builtin_amdgcn_mfma_f32_16x16x32_bf16(a1[m][k2], b1[n][k2], acc[m + 4][n + 2], 0, 0, 0);
    __builtin_amdgcn_s_setprio(0);
    __builtin_amdgcn_s_barrier();  // all reads of buf bc retired before overwrite

    bc ^= 1;
  }

  // C/D layout: col = lane&15, row = (lane>>4)*4 + reg
  float* Cb = P + (size_t)(bm * 256 + wm * 128) * DOUT + bn * 256 + wn * 64;
#pragma unroll
  for (int m = 0; m < 8; ++m)
#pragma unroll
    for (int n = 0; n < 4; ++n)
#pragma unroll
      for (int j = 0; j < 4; ++j)
        Cb[(size_t)(m * 16 + lk * 4 + j) * DOUT + n * 16 + l16] = acc[m][n][j];
}

// Fused partial-sum + LayerNorm + SE gate, one WAVE per token, all-register.
__global__ __launch_bounds__(256) void ln_se_fused(
    float* __restrict__ out, const float* __restrict__ p1,
    const float* __restrict__ ln_w, const float* __restrict__ ln_b,
    const ushort* __restrict__ w1b, const float* __restrict__ se_b1,
    const ushort* __restrict__ w2b, const float* __restrict__ se_b2) {
  const int lane = threadIdx.x & 63;
  const int t = blockIdx.x * 4 + (threadIdx.x >> 6);
  float* row = out + (size_t)t * DOUT;
  const float* row1 = p1 + (size_t)t * DOUT;

  float y[16];
#pragma unroll
  for (int h = 0; h < 2; ++h) {
    const float4 a = ((const float4*)row)[(lane + 64 * h) * 2];
    const float4 b = ((const float4*)row)[(lane + 64 * h) * 2 + 1];
    const float4 c = ((const float4*)row1)[(lane + 64 * h) * 2];
    const float4 d = ((const float4*)row1)[(lane + 64 * h) * 2 + 1];
    y[h * 8 + 0] = a.x + c.x; y[h * 8 + 1] = a.y + c.y;
    y[h * 8 + 2] = a.z + c.z; y[h * 8 + 3] = a.w + c.w;
    y[h * 8 + 4] = b.x + d.x; y[h * 8 + 5] = b.y + d.y;
    y[h * 8 + 6] = b.z + d.z; y[h * 8 + 7] = b.w + d.w;
  }
  float s = 0.f, ss = 0.f;
#pragma unroll
  for (int e = 0; e < 16; ++e) { s += y[e]; ss += y[e] * y[e]; }
#pragma unroll
  for (int m = 32; m; m >>= 1) { s += __shfl_xor(s, m); ss += __shfl_xor(ss, m); }
  const float mu = s * (1.f / (float)DOUT);
  const float inv = rsqrtf(ss * (1.f / (float)DOUT) - mu * mu + 1e-5f);

#pragma unroll
  for (int h = 0; h < 2; ++h) {
    const float4 lw0 = ((const float4*)ln_w)[(lane + 64 * h) * 2];
    const float4 lw1 = ((const float4*)ln_w)[(lane + 64 * h) * 2 + 1];
    const float4 lb0 = ((const float4*)ln_b)[(lane + 64 * h) * 2];
    const float4 lb1 = ((const float4*)ln_b)[(lane + 64 * h) * 2 + 1];
    y[h * 8 + 0] = (y[h * 8 + 0] - mu) * inv * lw0.x + lb0.x;
    y[h * 8 + 1] = (y[h * 8 + 1] - mu) * inv * lw0.y + lb0.y;
    y[h * 8 + 2] = (y[h * 8 + 2] - mu) * inv * lw0.z + lb0.z;
    y[h * 8 + 3] = (y[h * 8 + 3] - mu) * inv * lw0.w + lb0.w;
    y[h * 8 + 4] = (y[h * 8 + 4] - mu) * inv * lw1.x + lb1.x;
    y[h * 8 + 5] = (y[h * 8 + 5] - mu) * inv * lw1.y + lb1.y;
    y[h * 8 + 6] = (y[h * 8 + 6] - mu) * inv * lw1.z + lb1.z;
    y[h * 8 + 7] = (y[h * 8 + 7] - mu) * inv * lw1.w + lb1.w;
  }

  float hj[32];
#pragma unroll
  for (int j = 0; j < 32; ++j) {
    float p = 0.f;
#pragma unroll
    for (int h = 0; h < 2; ++h) {
      const uint4 w = *(const uint4*)(w1b + j * DOUT + (lane + 64 * h) * 8);
      p += y[h * 8 + 0] * bflo(w.x) + y[h * 8 + 1] * bfhi(w.x)
         + y[h * 8 + 2] * bflo(w.y) + y[h * 8 + 3] * bfhi(w.y)
         + y[h * 8 + 4] * bflo(w.z) + y[h * 8 + 5] * bfhi(w.z)
         + y[h * 8 + 6] * bflo(w.w) + y[h * 8 + 7] * bfhi(w.w);
    }
    hj[j] = p;
  }
#pragma unroll
  for (int m = 32; m; m >>= 1)
#pragma unroll
    for (int j = 0; j < 32; ++j) hj[j] += __shfl_xor(hj[j], m);
#pragma unroll
  for (int j = 0; j < 32; ++j) hj[j] = fmaxf(hj[j] + se_b1[j], 0.f);

#pragma unroll
  for (int h = 0; h < 2; ++h) {
    float o[8];
#pragma unroll
    for (int e = 0; e < 8; ++e) {
      const int c = (lane + 64 * h) * 8 + e;
      const uint4* wp = (const uint4*)(w2b + (size_t)c * SEH);
      const uint4 wa = wp[0], wb = wp[1], wc2 = wp[2], wd = wp[3];
      float g = se_b2[c];
      g += hj[0] * bflo(wa.x) + hj[1] * bfhi(wa.x) + hj[2] * bflo(wa.y) + hj[3] * bfhi(wa.y)
         + hj[4] * bflo(wa.z) + hj[5] * bfhi(wa.z) + hj[6] * bflo(wa.w) + hj[7] * bfhi(wa.w);
      g += hj[8] * bflo(wb.x) + hj[9] * bfhi(wb.x) + hj[10] * bflo(wb.y) + hj[11] * bfhi(wb.y)
         + hj[12] * bflo(wb.z) + hj[13] * bfhi(wb.z) + hj[14] * bflo(wb.w) + hj[15] * bfhi(wb.w);
      g += hj[16] * bflo(wc2.x) + hj[17] * bfhi(wc2.x) + hj[18] * bflo(wc2.y) + hj[19] * bfhi(wc2.y)
         + hj[20] * bflo(wc2.z) + hj[21] * bfhi(wc2.z) + hj[22] * bflo(wc2.w) + hj[23] * bfhi(wc2.w);
      g += hj[24] * bflo(wd.x) + hj[25] * bfhi(wd.x) + hj[26] * bflo(wd.y) + hj[27] * bfhi(wd.y)
         + hj[28] * bflo(wd.z) + hj[29] * bfhi(wd.z) + hj[30] * bflo(wd.w) + hj[31] * bfhi(wd.w);
      o[e] = y[h * 8 + e] / (1.f + __expf(-g));
    }
    float4 s0, s1;
    s0.x = o[0]; s0.y = o[1]; s0.z = o[2]; s0.w = o[3];
    s1.x = o[4]; s1.y = o[5]; s1.z = o[6]; s1.w = o[7];
    ((float4*)row)[(lane + 64 * h) * 2] = s0;
    ((float4*)row)[(lane + 64 * h) * 2 + 1] = s1;
  }
}

extern "C" void kernel_launch(void* const* d_in, const int* in_sizes, int n_in,
                              void* d_out, int out_size, void* d_ws, size_t ws_size,
                              hipStream_t stream) {
  const float* x = (const float*)d_in[0];
  const float* bw = (const float*)d_in[1];
  const float* sw = (const float*)d_in[2];
  const float* ln_w = (const float*)d_in[3];
  const float* ln_b = (const float*)d_in[4];
  const float* se_w1 = (const float*)d_in[5];
  const float* se_b1 = (const float*)d_in[6];
  const float* se_w2 = (const float*)d_in[7];
  const float* se_b2 = (const float*)d_in[8];
  float* out = (float*)d_out;

  ushort* Aaug = (ushort*)d_ws;                        // 64 MB
  ushort* Waug = Aaug + (size_t)NTOK * KAUG;           // 8 MB
  ushort* w1b = Waug + (size_t)DOUT * KAUG;            // 64 KB
  ushort* w2b = w1b + SEH * DOUT;                      // 64 KB
  float* P1 = (float*)(w2b + SEH * DOUT);              // 32 MB (K-half-1 partial)

  build_aaug<<<NTOK * DIN / 256, 256, 0, stream>>>(x, Aaug);
  pack_w<<<DOUT * DIN / 256, 256, 0, stream>>>(bw, sw, Waug);
  pack_se<<<2 * SEH * DOUT / 256, 256, 0, stream>>>(se_w1, se_w2, w1b, w2b);
  gemm_sk<<<256, 512, 0, stream>>>(Aaug, Waug, out, P1);
  ln_se_fused<<<NTOK / 4, 256, 0, stream>>>(out, P1, ln_w, ln_b, w1b, se_b1, w2b, se_b2);
}

// Round 5
// 123.767 us; speedup vs baseline: 1.7885x; 1.4853x over previous
//
#include <hip/hip_runtime.h>
#include <hip/hip_bf16.h>
#include <math.h>

typedef __attribute__((ext_vector_type(8))) __bf16 bf16x8;
typedef __attribute__((ext_vector_type(4))) float f32x4;

#define NTOK 8192
#define DIN 1024
#define DOUT 1024
#define KAUG 4096
#define SEH 32

#define BK 64
#define KHALF 2048
#define NKT (KHALF / BK)  // 32

static __device__ __forceinline__ unsigned short f2bf(float f) {
  union { float f; unsigned u; } v; v.f = f;
  unsigned r = (v.u + 0x7FFFu + ((v.u >> 16) & 1u)) >> 16;
  return (unsigned short)r;
}

// A_aug[n][i*4 + {0..3}] = { x, b0/s, b1/s, b2/s }  (bf16)
__global__ __launch_bounds__(256) void build_aaug(const float* __restrict__ x,
                                                  ushort* __restrict__ Aaug) {
  const int id = blockIdx.x * 256 + threadIdx.x;
  const float v = x[id];
  const float d0 = fabsf(v + 1.f), d1 = fabsf(v), d2 = fabsf(v - 1.f);
  float b0 = (d0 < 1.f) ? (1.f - d0) * (1.f - d0) : 0.f;
  float b1 = (d1 < 1.f) ? (1.f - d1) * (1.f - d1) : 0.f;
  float b2 = (d2 < 1.f) ? (1.f - d2) * (1.f - d2) : 0.f;
  const float inv = 1.f / (b0 + b1 + b2 + 1e-6f);
  ushort4 o;
  o.x = f2bf(v);
  o.y = f2bf(b0 * inv);
  o.z = f2bf(b1 * inv);
  o.w = f2bf(b2 * inv);
  ((ushort4*)Aaug)[id] = o;
}

// W_aug[o][i*4 + {0..3}] = { base_w[o,i], spline_w[o,i,0..2] }  (bf16)
__global__ __launch_bounds__(256) void pack_w(const float* __restrict__ bw,
                                              const float* __restrict__ sw,
                                              ushort* __restrict__ Waug) {
  const int id = blockIdx.x * 256 + threadIdx.x;
  ushort4 o;
  o.x = f2bf(bw[id]);
  o.y = f2bf(sw[id * 3 + 0]);
  o.z = f2bf(sw[id * 3 + 1]);
  o.w = f2bf(sw[id * 3 + 2]);
  ((ushort4*)Waug)[id] = o;
}

__global__ __launch_bounds__(256) void pack_se(const float* __restrict__ w1,
                                               const float* __restrict__ w2,
                                               ushort* __restrict__ w1b,
                                               ushort* __restrict__ w2b) {
  const int id = blockIdx.x * 256 + threadIdx.x;
  if (id < SEH * DOUT) w1b[id] = f2bf(w1[id]);
  else w2b[id - SEH * DOUT] = f2bf(w2[id - SEH * DOUT]);
}

#define WAITVM(N) asm volatile("s_waitcnt vmcnt(" #N ")" ::: "memory")

// Split-K GEMM: C-tile 256x256, K split in 2 halves of 2048.
// 8 waves (2M x 4N), per-wave 128x64 (acc[8][4]). Double-buffered 128KB LDS.
__global__ __launch_bounds__(512, 2) void gemm_sk(const ushort* __restrict__ A,
                                                  const ushort* __restrict__ B,
                                                  float* __restrict__ P0,
                                                  float* __restrict__ P1) {
  __shared__ ushort As[2][256 * BK];
  __shared__ ushort Bs[2][256 * BK];
  const int tid = threadIdx.x;
  const int wid = tid >> 6, lane = tid & 63;
  const int l16 = lane & 15, lk = lane >> 4;
  const int wm = wid >> 2, wn = wid & 3;

  const int g = (blockIdx.x & 7) * 32 + (blockIdx.x >> 3);
  const int kh = g >> 7;
  const int bm = (g & 127) >> 2;
  const int bn = g & 3;

  const ushort* Ab = A + (size_t)bm * 256 * KAUG + kh * KHALF;
  const ushort* Bb = B + (size_t)bn * 256 * KAUG + kh * KHALF;
  float* P = kh ? P1 : P0;

  const int lrow = lane >> 3;
  const int lcb = (lane & 7) ^ lrow;

  f32x4 acc[8][4] = {};

#define STAGE_A(kt, buf, r)                                                     \
  __builtin_amdgcn_global_load_lds(                                             \
      (const __attribute__((address_space(1))) void*)(Ab +                      \
          (size_t)((r) * 64 + wid * 8 + lrow) * KAUG + (kt) * BK + lcb * 8),    \
      (__attribute__((address_space(3))) void*)(&As[buf][((r) * 512 + wid * 64) * 8]), \
      16, 0, 0)
#define STAGE_B(kt, buf, r)                                                     \
  __builtin_amdgcn_global_load_lds(                                             \
      (const __attribute__((address_space(1))) void*)(Bb +                      \
          (size_t)((r) * 64 + wid * 8 + lrow) * KAUG + (kt) * BK + lcb * 8),    \
      (__attribute__((address_space(3))) void*)(&Bs[buf][((r) * 512 + wid * 64) * 8]), \
      16, 0, 0)
#define STAGE_ALL(kt, buf)                                                      \
  do {                                                                          \
    STAGE_A(kt, buf, 0); STAGE_A(kt, buf, 1); STAGE_A(kt, buf, 2); STAGE_A(kt, buf, 3); \
    STAGE_B(kt, buf, 0); STAGE_B(kt, buf, 1); STAGE_B(kt, buf, 2); STAGE_B(kt, buf, 3); \
  } while (0)

#define RD_A(buf, m, kk) \
  (*(const bf16x8*)&As[buf][(wm * 128 + (m) * 16 + l16) * 64 + ((((kk) * 4 + lk) ^ (l16 & 7)) << 3)])
#define RD_B(buf, n, kk) \
  (*(const bf16x8*)&Bs[buf][(wn * 64 + (n) * 16 + l16) * 64 + ((((kk) * 4 + lk) ^ (l16 & 7)) << 3)])

  STAGE_ALL(0, 0);

  int bc = 0;
  for (int kt = 0; kt < NKT; ++kt) {
    if (kt < NKT - 1) {
      STAGE_ALL(kt + 1, bc ^ 1);
      WAITVM(8);
    } else {
      WAITVM(0);
    }
    __builtin_amdgcn_s_barrier();

    bf16x8 a0[4][2], a1[4][2], b0[2][2], b1[2][2];
#pragma unroll
    for (int m = 0; m < 4; ++m) { a0[m][0] = RD_A(bc, m, 0); a0[m][1] = RD_A(bc, m, 1); }
#pragma unroll
    for (int n = 0; n < 2; ++n) { b0[n][0] = RD_B(bc, n, 0); b0[n][1] = RD_B(bc, n, 1); }
    __builtin_amdgcn_s_setprio(1);
#pragma unroll
    for (int m = 0; m < 4; ++m)
#pragma unroll
      for (int n = 0; n < 2; ++n)
#pragma unroll
        for (int k2 = 0; k2 < 2; ++k2)
          acc[m][n] = __builtin_amdgcn_mfma_f32_16x16x32_bf16(a0[m][k2], b0[n][k2], acc[m][n], 0, 0, 0);
    __builtin_amdgcn_s_setprio(0);
    __builtin_amdgcn_s_barrier();

#pragma unroll
    for (int n = 0; n < 2; ++n) { b1[n][0] = RD_B(bc, n + 2, 0); b1[n][1] = RD_B(bc, n + 2, 1); }
    __builtin_amdgcn_s_setprio(1);
#pragma unroll
    for (int m = 0; m < 4; ++m)
#pragma unroll
      for (int n = 0; n < 2; ++n)
#pragma unroll
        for (int k2 = 0; k2 < 2; ++k2)
          acc[m][n + 2] = __builtin_amdgcn_mfma_f32_16x16x32_bf16(a0[m][k2], b1[n][k2], acc[m][n + 2], 0, 0, 0);
    __builtin_amdgcn_s_setprio(0);
    __builtin_amdgcn_s_barrier();

#pragma unroll
    for (int m = 0; m < 4; ++m) { a1[m][0] = RD_A(bc, m + 4, 0); a1[m][1] = RD_A(bc, m + 4, 1); }
    __builtin_amdgcn_s_setprio(1);
#pragma unroll
    for (int m = 0; m < 4; ++m)
#pragma unroll
      for (int n = 0; n < 2; ++n)
#pragma unroll
        for (int k2 = 0; k2 < 2; ++k2)
          acc[m + 4][n] = __builtin_amdgcn_mfma_f32_16x16x32_bf16(a1[m][k2], b0[n][k2], acc[m + 4][n], 0, 0, 0);
    __builtin_amdgcn_s_setprio(0);
    __builtin_amdgcn_s_barrier();

    __builtin_amdgcn_s_setprio(1);
#pragma unroll
    for (int m = 0; m < 4; ++m)
#pragma unroll
      for (int n = 0; n < 2; ++n)
#pragma unroll
        for (int k2 = 0; k2 < 2; ++k2)
          acc[m + 4][n + 2] = __builtin_amdgcn_mfma_f32_16x16x32_bf16(a1[m][k2], b1[n][k2], acc[m + 4][n + 2], 0, 0, 0);
    __builtin_amdgcn_s_setprio(0);
    __builtin_amdgcn_s_barrier();

    bc ^= 1;
  }

  float* Cb = P + (size_t)(bm * 256 + wm * 128) * DOUT + bn * 256 + wn * 64;
#pragma unroll
  for (int m = 0; m < 8; ++m)
#pragma unroll
    for (int n = 0; n < 4; ++n)
#pragma unroll
      for (int j = 0; j < 4; ++j)
        Cb[(size_t)(m * 16 + lk * 4 + j) * DOUT + n * 16 + l16] = acc[m][n][j];
}

// Fused partial-sum + LayerNorm + SE (both SE matmuls on MFMA).
// 16 tokens/block, 4 waves. Y kept f32 in LDS; weights bf16 read from L2.
__global__ __launch_bounds__(256) void ln_se_mfma(
    float* __restrict__ out, const float* __restrict__ p1,
    const float* __restrict__ ln_w, const float* __restrict__ ln_b,
    const ushort* __restrict__ w1b, const float* __restrict__ se_b1,
    const ushort* __restrict__ w2b, const float* __restrict__ se_b2) {
  __shared__ float Yl[16 * 1028];       // 16 tokens x 1024 (+4 pad) f32
  __shared__ float Hpart[4][512];       // per-wave SE1 partials (16x32)
  __shared__ unsigned Hb[256];          // H packed bf16 [16 tok][16 u32]
  const int tid = threadIdx.x;
  const int w = tid >> 6, lane = tid & 63;
  const int l16 = lane & 15, lk = lane >> 4;
  const int tok0 = blockIdx.x * 16;

  // LN params: lane owns cols e*64+lane (coalesced, conflict-free LDS writes)
  float lw[16], lb[16];
#pragma unroll
  for (int e = 0; e < 16; ++e) {
    lw[e] = ln_w[e * 64 + lane];
    lb[e] = ln_b[e * 64 + lane];
  }

  // LN: wave w handles tokens w*4 .. w*4+3
  for (int q = 0; q < 4; ++q) {
    const int tl = w * 4 + q;
    const float* r0 = out + (size_t)(tok0 + tl) * DOUT;
    const float* r1 = p1 + (size_t)(tok0 + tl) * DOUT;
    float v[16];
#pragma unroll
    for (int e = 0; e < 16; ++e) v[e] = r0[e * 64 + lane] + r1[e * 64 + lane];
    float s = 0.f, ss = 0.f;
#pragma unroll
    for (int e = 0; e < 16; ++e) { s += v[e]; ss += v[e] * v[e]; }
#pragma unroll
    for (int m = 32; m; m >>= 1) { s += __shfl_xor(s, m); ss += __shfl_xor(ss, m); }
    const float mu = s * (1.f / (float)DOUT);
    const float inv = rsqrtf(ss * (1.f / (float)DOUT) - mu * mu + 1e-5f);
#pragma unroll
    for (int e = 0; e < 16; ++e)
      Yl[tl * 1028 + e * 64 + lane] = (v[e] - mu) * inv * lw[e] + lb[e];
  }
  __syncthreads();

  // SE1: H[16 tok][32 hid] = Y[16][1024] @ w1^T. K split across waves (256 each).
  f32x4 acc1[2] = {};
#pragma unroll
  for (int s = 0; s < 8; ++s) {
    const int ks = w * 8 + s;               // k-step (32 wide)
    const int k = ks * 32 + lk * 8;
    const float* yp = &Yl[l16 * 1028 + k];  // A-frag: token=l16, k-chunk=lk
    const f32x4 q0 = *(const f32x4*)yp;
    const f32x4 q1 = *(const f32x4*)(yp + 4);
    bf16x8 af;
    af[0] = (__bf16)q0[0]; af[1] = (__bf16)q0[1];
    af[2] = (__bf16)q0[2]; af[3] = (__bf16)q0[3];
    af[4] = (__bf16)q1[0]; af[5] = (__bf16)q1[1];
    af[6] = (__bf16)q1[2]; af[7] = (__bf16)q1[3];
#pragma unroll
    for (int nt = 0; nt < 2; ++nt) {
      const bf16x8 bf = *(const bf16x8*)(w1b + (nt * 16 + l16) * 1024 + ks * 32 + lk * 8);
      acc1[nt] = __builtin_amdgcn_mfma_f32_16x16x32_bf16(af, bf, acc1[nt], 0, 0, 0);
    }
  }
#pragma unroll
  for (int nt = 0; nt < 2; ++nt)
#pragma unroll
    for (int j = 0; j < 4; ++j)
      Hpart[w][(lk * 4 + j) * 32 + nt * 16 + l16] = acc1[nt][j];
  __syncthreads();

  // reduce partials + bias + relu + pack to bf16 pairs
  {
    const int e2 = tid * 2;
    float h0 = Hpart[0][e2] + Hpart[1][e2] + Hpart[2][e2] + Hpart[3][e2];
    float h1 = Hpart[0][e2 + 1] + Hpart[1][e2 + 1] + Hpart[2][e2 + 1] + Hpart[3][e2 + 1];
    h0 = fmaxf(h0 + se_b1[e2 & 31], 0.f);
    h1 = fmaxf(h1 + se_b1[(e2 & 31) + 1], 0.f);
    Hb[tid] = (unsigned)f2bf(h0) | ((unsigned)f2bf(h1) << 16);
  }
  __syncthreads();

  // SE2: G[16 tok][1024] = H[16][32] @ w2^T, N split across waves (256 each).
  union { uint4 u; bf16x8 v; } ha;
  ha.u = *(const uint4*)&Hb[l16 * 16 + lk * 4];  // A-frag: token=l16, k=lk*8..
  const int nbase = w * 256;
#pragma unroll
  for (int nt = 0; nt < 16; ++nt) {
    const int col = nbase + nt * 16 + l16;
    const bf16x8 bf = *(const bf16x8*)(w2b + col * 32 + lk * 8);
    f32x4 gz = {0.f, 0.f, 0.f, 0.f};
    gz = __builtin_amdgcn_mfma_f32_16x16x32_bf16(ha.v, bf, gz, 0, 0, 0);
    const float b2 = se_b2[col];
#pragma unroll
    for (int j = 0; j < 4; ++j) {
      const int tl = lk * 4 + j;
      const float sg = 1.f / (1.f + __expf(-(gz[j] + b2)));
      out[(size_t)(tok0 + tl) * DOUT + col] = Yl[tl * 1028 + col] * sg;
    }
  }
}

extern "C" void kernel_launch(void* const* d_in, const int* in_sizes, int n_in,
                              void* d_out, int out_size, void* d_ws, size_t ws_size,
                              hipStream_t stream) {
  const float* x = (const float*)d_in[0];
  const float* bw = (const float*)d_in[1];
  const float* sw = (const float*)d_in[2];
  const float* ln_w = (const float*)d_in[3];
  const float* ln_b = (const float*)d_in[4];
  const float* se_w1 = (const float*)d_in[5];
  const float* se_b1 = (const float*)d_in[6];
  const float* se_w2 = (const float*)d_in[7];
  const float* se_b2 = (const float*)d_in[8];
  float* out = (float*)d_out;

  ushort* Aaug = (ushort*)d_ws;                        // 64 MB
  ushort* Waug = Aaug + (size_t)NTOK * KAUG;           // 8 MB
  ushort* w1b = Waug + (size_t)DOUT * KAUG;            // 64 KB
  ushort* w2b = w1b + SEH * DOUT;                      // 64 KB
  float* P1 = (float*)(w2b + SEH * DOUT);              // 32 MB (K-half-1 partial)

  build_aaug<<<NTOK * DIN / 256, 256, 0, stream>>>(x, Aaug);
  pack_w<<<DOUT * DIN / 256, 256, 0, stream>>>(bw, sw, Waug);
  pack_se<<<2 * SEH * DOUT / 256, 256, 0, stream>>>(se_w1, se_w2, w1b, w2b);
  gemm_sk<<<256, 512, 0, stream>>>(Aaug, Waug, out, P1);
  ln_se_mfma<<<NTOK / 16, 256, 0, stream>>>(out, P1, ln_w, ln_b, w1b, se_b1, w2b, se_b2);
}

// Round 7
// 119.986 us; speedup vs baseline: 1.8449x; 1.0315x over previous
//
#include <hip/hip_runtime.h>
#include <hip/hip_bf16.h>
#include <math.h>

typedef __attribute__((ext_vector_type(8))) __bf16 bf16x8;
typedef __attribute__((ext_vector_type(4))) float f32x4;

#define NTOK 8192
#define DIN 1024
#define DOUT 1024
#define KAUG 4096
#define SEH 32

#define BK 64
#define KHALF 2048
#define NKT (KHALF / BK)  // 32

static __device__ __forceinline__ unsigned short f2bf(float f) {
  union { float f; unsigned u; } v; v.f = f;
  unsigned r = (v.u + 0x7FFFu + ((v.u >> 16) & 1u)) >> 16;
  return (unsigned short)r;
}

// A_aug[n][i*4 + {0..3}] = { x, b0/s, b1/s, b2/s }  (bf16)
__global__ __launch_bounds__(256) void build_aaug(const float* __restrict__ x,
                                                  ushort* __restrict__ Aaug) {
  const int id = blockIdx.x * 256 + threadIdx.x;
  const float v = x[id];
  const float d0 = fabsf(v + 1.f), d1 = fabsf(v), d2 = fabsf(v - 1.f);
  float b0 = (d0 < 1.f) ? (1.f - d0) * (1.f - d0) : 0.f;
  float b1 = (d1 < 1.f) ? (1.f - d1) * (1.f - d1) : 0.f;
  float b2 = (d2 < 1.f) ? (1.f - d2) * (1.f - d2) : 0.f;
  const float inv = 1.f / (b0 + b1 + b2 + 1e-6f);
  ushort4 o;
  o.x = f2bf(v);
  o.y = f2bf(b0 * inv);
  o.z = f2bf(b1 * inv);
  o.w = f2bf(b2 * inv);
  ((ushort4*)Aaug)[id] = o;
}

// W_aug[o][i*4 + {0..3}] = { base_w[o,i], spline_w[o,i,0..2] }  (bf16)
__global__ __launch_bounds__(256) void pack_w(const float* __restrict__ bw,
                                              const float* __restrict__ sw,
                                              ushort* __restrict__ Waug) {
  const int id = blockIdx.x * 256 + threadIdx.x;
  ushort4 o;
  o.x = f2bf(bw[id]);
  o.y = f2bf(sw[id * 3 + 0]);
  o.z = f2bf(sw[id * 3 + 1]);
  o.w = f2bf(sw[id * 3 + 2]);
  ((ushort4*)Waug)[id] = o;
}

__global__ __launch_bounds__(256) void pack_se(const float* __restrict__ w1,
                                               const float* __restrict__ w2,
                                               ushort* __restrict__ w1b,
                                               ushort* __restrict__ w2b) {
  const int id = blockIdx.x * 256 + threadIdx.x;
  if (id < SEH * DOUT) w1b[id] = f2bf(w1[id]);
  else w2b[id - SEH * DOUT] = f2bf(w2[id - SEH * DOUT]);
}

#define WAITVM(N) asm volatile("s_waitcnt vmcnt(" #N ")" ::: "memory")

// Split-K GEMM: C-tile 256x256, K split in 2 halves of 2048.
// 8 waves (2M x 4N), per-wave 128x64 (acc[8][4]). Double-buffered 128KB LDS.
// R5 sync skeleton (validated): STAGE_ALL at tile top, WAITVM(8), entry barrier,
// exit barrier. This revision deletes the 3 intra-tile barriers (register-only
// regions between them) and orders MFMAs k2-outermost (32 indep accs).
__global__ __launch_bounds__(512, 2) void gemm_sk(const ushort* __restrict__ A,
                                                  const ushort* __restrict__ B,
                                                  float* __restrict__ P0,
                                                  float* __restrict__ P1) {
  __shared__ ushort As[2][256 * BK];
  __shared__ ushort Bs[2][256 * BK];
  const int tid = threadIdx.x;
  const int wid = tid >> 6, lane = tid & 63;
  const int l16 = lane & 15, lk = lane >> 4;
  const int wm = wid >> 2, wn = wid & 3;

  const int g = (blockIdx.x & 7) * 32 + (blockIdx.x >> 3);
  const int kh = g >> 7;
  const int bm = (g & 127) >> 2;
  const int bn = g & 3;

  const ushort* Ab = A + (size_t)bm * 256 * KAUG + kh * KHALF;
  const ushort* Bb = B + (size_t)bn * 256 * KAUG + kh * KHALF;
  float* P = kh ? P1 : P0;

  const int lrow = lane >> 3;
  const int lcb = (lane & 7) ^ lrow;

  f32x4 acc[8][4] = {};

#define STAGE_A(kt, buf, r)                                                     \
  __builtin_amdgcn_global_load_lds(                                             \
      (const __attribute__((address_space(1))) void*)(Ab +                      \
          (size_t)((r) * 64 + wid * 8 + lrow) * KAUG + (kt) * BK + lcb * 8),    \
      (__attribute__((address_space(3))) void*)(&As[buf][((r) * 512 + wid * 64) * 8]), \
      16, 0, 0)
#define STAGE_B(kt, buf, r)                                                     \
  __builtin_amdgcn_global_load_lds(                                             \
      (const __attribute__((address_space(1))) void*)(Bb +                      \
          (size_t)((r) * 64 + wid * 8 + lrow) * KAUG + (kt) * BK + lcb * 8),    \
      (__attribute__((address_space(3))) void*)(&Bs[buf][((r) * 512 + wid * 64) * 8]), \
      16, 0, 0)
#define STAGE_ALL(kt, buf)                                                      \
  do {                                                                          \
    STAGE_A(kt, buf, 0); STAGE_A(kt, buf, 1); STAGE_A(kt, buf, 2); STAGE_A(kt, buf, 3); \
    STAGE_B(kt, buf, 0); STAGE_B(kt, buf, 1); STAGE_B(kt, buf, 2); STAGE_B(kt, buf, 3); \
  } while (0)

#define RD_A(buf, m, kk) \
  (*(const bf16x8*)&As[buf][(wm * 128 + (m) * 16 + l16) * 64 + ((((kk) * 4 + lk) ^ (l16 & 7)) << 3)])
#define RD_B(buf, n, kk) \
  (*(const bf16x8*)&Bs[buf][(wn * 64 + (n) * 16 + l16) * 64 + ((((kk) * 4 + lk) ^ (l16 & 7)) << 3)])

  // prologue: stage tile 0 into buf 0
  STAGE_ALL(0, 0);

  int bc = 0;
  for (int kt = 0; kt < NKT; ++kt) {
    if (kt < NKT - 1) {
      STAGE_ALL(kt + 1, bc ^ 1);
      WAITVM(8);   // drains tile kt's 8 loads; next tile's 8 stay in flight
    } else {
      WAITVM(0);
    }
    __builtin_amdgcn_s_barrier();        // entry: tile kt visible to all waves
    __builtin_amdgcn_sched_barrier(0);   // pin reads below the sync point

    bf16x8 af[8][2], bfr[4][2];
#pragma unroll
    for (int m = 0; m < 8; ++m) { af[m][0] = RD_A(bc, m, 0); af[m][1] = RD_A(bc, m, 1); }
#pragma unroll
    for (int n = 0; n < 4; ++n) { bfr[n][0] = RD_B(bc, n, 0); bfr[n][1] = RD_B(bc, n, 1); }

    __builtin_amdgcn_s_setprio(1);
#pragma unroll
    for (int k2 = 0; k2 < 2; ++k2)
#pragma unroll
      for (int m = 0; m < 8; ++m)
#pragma unroll
        for (int n = 0; n < 4; ++n)
          acc[m][n] = __builtin_amdgcn_mfma_f32_16x16x32_bf16(af[m][k2], bfr[n][k2], acc[m][n], 0, 0, 0);
    __builtin_amdgcn_s_setprio(0);

    __builtin_amdgcn_s_barrier();        // exit: reads retired before buf reuse
    bc ^= 1;
  }

  // C/D layout: col = lane&15, row = (lane>>4)*4 + reg
  float* Cb = P + (size_t)(bm * 256 + wm * 128) * DOUT + bn * 256 + wn * 64;
#pragma unroll
  for (int m = 0; m < 8; ++m)
#pragma unroll
    for (int n = 0; n < 4; ++n)
#pragma unroll
      for (int j = 0; j < 4; ++j)
        Cb[(size_t)(m * 16 + lk * 4 + j) * DOUT + n * 16 + l16] = acc[m][n][j];
}

// Fused partial-sum + LayerNorm + SE (both SE matmuls on MFMA).
// 16 tokens/block, 4 waves. Y kept f32 in LDS; weights bf16 read from L2.
__global__ __launch_bounds__(256) void ln_se_mfma(
    float* __restrict__ out, const float* __restrict__ p1,
    const float* __restrict__ ln_w, const float* __restrict__ ln_b,
    const ushort* __restrict__ w1b, const float* __restrict__ se_b1,
    const ushort* __restrict__ w2b, const float* __restrict__ se_b2) {
  __shared__ float Yl[16 * 1028];       // 16 tokens x 1024 (+4 pad) f32
  __shared__ float Hpart[4][512];       // per-wave SE1 partials (16x32)
  __shared__ unsigned Hb[256];          // H packed bf16 [16 tok][16 u32]
  const int tid = threadIdx.x;
  const int w = tid >> 6, lane = tid & 63;
  const int l16 = lane & 15, lk = lane >> 4;
  const int tok0 = blockIdx.x * 16;

  float lw[16], lb[16];
#pragma unroll
  for (int e = 0; e < 16; ++e) {
    lw[e] = ln_w[e * 64 + lane];
    lb[e] = ln_b[e * 64 + lane];
  }

  for (int q = 0; q < 4; ++q) {
    const int tl = w * 4 + q;
    const float* r0 = out + (size_t)(tok0 + tl) * DOUT;
    const float* r1 = p1 + (size_t)(tok0 + tl) * DOUT;
    float v[16];
#pragma unroll
    for (int e = 0; e < 16; ++e) v[e] = r0[e * 64 + lane] + r1[e * 64 + lane];
    float s = 0.f, ss = 0.f;
#pragma unroll
    for (int e = 0; e < 16; ++e) { s += v[e]; ss += v[e] * v[e]; }
#pragma unroll
    for (int m = 32; m; m >>= 1) { s += __shfl_xor(s, m); ss += __shfl_xor(ss, m); }
    const float mu = s * (1.f / (float)DOUT);
    const float inv = rsqrtf(ss * (1.f / (float)DOUT) - mu * mu + 1e-5f);
#pragma unroll
    for (int e = 0; e < 16; ++e)
      Yl[tl * 1028 + e * 64 + lane] = (v[e] - mu) * inv * lw[e] + lb[e];
  }
  __syncthreads();

  // SE1: H[16 tok][32 hid] = Y[16][1024] @ w1^T. K split across waves (256 each).
  f32x4 acc1[2] = {};
#pragma unroll
  for (int s = 0; s < 8; ++s) {
    const int ks = w * 8 + s;
    const int k = ks * 32 + lk * 8;
    const float* yp = &Yl[l16 * 1028 + k];
    const f32x4 q0 = *(const f32x4*)yp;
    const f32x4 q1 = *(const f32x4*)(yp + 4);
    bf16x8 af;
    af[0] = (__bf16)q0[0]; af[1] = (__bf16)q0[1];
    af[2] = (__bf16)q0[2]; af[3] = (__bf16)q0[3];
    af[4] = (__bf16)q1[0]; af[5] = (__bf16)q1[1];
    af[6] = (__bf16)q1[2]; af[7] = (__bf16)q1[3];
#pragma unroll
    for (int nt = 0; nt < 2; ++nt) {
      const bf16x8 bf = *(const bf16x8*)(w1b + (nt * 16 + l16) * 1024 + ks * 32 + lk * 8);
      acc1[nt] = __builtin_amdgcn_mfma_f32_16x16x32_bf16(af, bf, acc1[nt], 0, 0, 0);
    }
  }
#pragma unroll
  for (int nt = 0; nt < 2; ++nt)
#pragma unroll
    for (int j = 0; j < 4; ++j)
      Hpart[w][(lk * 4 + j) * 32 + nt * 16 + l16] = acc1[nt][j];
  __syncthreads();

  {
    const int e2 = tid * 2;
    float h0 = Hpart[0][e2] + Hpart[1][e2] + Hpart[2][e2] + Hpart[3][e2];
    float h1 = Hpart[0][e2 + 1] + Hpart[1][e2 + 1] + Hpart[2][e2 + 1] + Hpart[3][e2 + 1];
    h0 = fmaxf(h0 + se_b1[e2 & 31], 0.f);
    h1 = fmaxf(h1 + se_b1[(e2 & 31) + 1], 0.f);
    Hb[tid] = (unsigned)f2bf(h0) | ((unsigned)f2bf(h1) << 16);
  }
  __syncthreads();

  // SE2: G[16 tok][1024] = H[16][32] @ w2^T, N split across waves (256 each).
  union { uint4 u; bf16x8 v; } ha;
  ha.u = *(const uint4*)&Hb[l16 * 16 + lk * 4];
  const int nbase = w * 256;
#pragma unroll
  for (int nt = 0; nt < 16; ++nt) {
    const int col = nbase + nt * 16 + l16;
    const bf16x8 bf = *(const bf16x8*)(w2b + col * 32 + lk * 8);
    f32x4 gz = {0.f, 0.f, 0.f, 0.f};
    gz = __builtin_amdgcn_mfma_f32_16x16x32_bf16(ha.v, bf, gz, 0, 0, 0);
    const float b2 = se_b2[col];
#pragma unroll
    for (int j = 0; j < 4; ++j) {
      const int tl = lk * 4 + j;
      const float sg = 1.f / (1.f + __expf(-(gz[j] + b2)));
      out[(size_t)(tok0 + tl) * DOUT + col] = Yl[tl * 1028 + col] * sg;
    }
  }
}

extern "C" void kernel_launch(void* const* d_in, const int* in_sizes, int n_in,
                              void* d_out, int out_size, void* d_ws, size_t ws_size,
                              hipStream_t stream) {
  const float* x = (const float*)d_in[0];
  const float* bw = (const float*)d_in[1];
  const float* sw = (const float*)d_in[2];
  const float* ln_w = (const float*)d_in[3];
  const float* ln_b = (const float*)d_in[4];
  const float* se_w1 = (const float*)d_in[5];
  const float* se_b1 = (const float*)d_in[6];
  const float* se_w2 = (const float*)d_in[7];
  const float* se_b2 = (const float*)d_in[8];
  float* out = (float*)d_out;

  ushort* Aaug = (ushort*)d_ws;                        // 64 MB
  ushort* Waug = Aaug + (size_t)NTOK * KAUG;           // 8 MB
  ushort* w1b = Waug + (size_t)DOUT * KAUG;            // 64 KB
  ushort* w2b = w1b + SEH * DOUT;                      // 64 KB
  float* P1 = (float*)(w2b + SEH * DOUT);              // 32 MB (K-half-1 partial)

  build_aaug<<<NTOK * DIN / 256, 256, 0, stream>>>(x, Aaug);
  pack_w<<<DOUT * DIN / 256, 256, 0, stream>>>(bw, sw, Waug);
  pack_se<<<2 * SEH * DOUT / 256, 256, 0, stream>>>(se_w1, se_w2, w1b, w2b);
  gemm_sk<<<256, 512, 0, stream>>>(Aaug, Waug, out, P1);
  ln_se_mfma<<<NTOK / 16, 256, 0, stream>>>(out, P1, ln_w, ln_b, w1b, se_b1, w2b, se_b2);
}